// Round 15
// baseline (181.445 us; speedup 1.0000x reference)
//
#include <hip/hip_runtime.h>
#include <hip/hip_bf16.h>

#define T_TOK 2048
#define HID 1024
#define FFNDIM 2048
#define NEXP 8

typedef __attribute__((ext_vector_type(8))) short short8;
typedef __attribute__((ext_vector_type(4))) float f32x4;

__device__ inline unsigned short f2bf(float f) {
  union { float f; unsigned int u; } v; v.f = f;
  unsigned int u = v.u;
  unsigned int r = (u + 0x7fffu + ((u >> 16) & 1u)) >> 16;
  return (unsigned short)r;
}

__device__ inline short8 pack8(float4 a, float4 b) {
  union { __hip_bfloat162 h2[4]; short8 s; } u;
  u.h2[0] = __float22bfloat162_rn(float2{a.x, a.y});
  u.h2[1] = __float22bfloat162_rn(float2{a.z, a.w});
  u.h2[2] = __float22bfloat162_rn(float2{b.x, b.y});
  u.h2[3] = __float22bfloat162_rn(float2{b.z, b.w});
  return u.s;
}

__device__ inline void gload_lds16(const void* g, void* l) {
  __builtin_amdgcn_global_load_lds((const __attribute__((address_space(1))) void*)g,
                                   (__attribute__((address_space(3))) void*)l, 16, 0, 0);
}

// ---------------- router: logits + top2 + bf16 x copy ----------------
__global__ __launch_bounds__(256) void router_kernel(
    const float* __restrict__ x, const float* __restrict__ gw,
    int* __restrict__ top_i, float* __restrict__ top_w,
    unsigned short* __restrict__ xbf) {
  int lane = threadIdx.x & 63;
  int t = blockIdx.x * 4 + (threadIdx.x >> 6);
  if (t >= T_TOK) return;
  float xv[16];
#pragma unroll
  for (int i = 0; i < 16; ++i) xv[i] = x[(size_t)t * HID + i * 64 + lane];
#pragma unroll
  for (int i = 0; i < 16; ++i) xbf[(size_t)t * HID + i * 64 + lane] = f2bf(xv[i]);
  float logit[NEXP];
#pragma unroll
  for (int e = 0; e < NEXP; ++e) {
    float s = 0.f;
#pragma unroll
    for (int i = 0; i < 16; ++i) s += xv[i] * gw[e * HID + i * 64 + lane];
#pragma unroll
    for (int off = 32; off > 0; off >>= 1) s += __shfl_xor(s, off);
    logit[e] = s;
  }
  if (lane == 0) {
    float mx = logit[0];
#pragma unroll
    for (int e = 1; e < NEXP; ++e) mx = fmaxf(mx, logit[e]);
    float p[NEXP]; float sum = 0.f;
#pragma unroll
    for (int e = 0; e < NEXP; ++e) { p[e] = expf(logit[e] - mx); sum += p[e]; }
#pragma unroll
    for (int e = 0; e < NEXP; ++e) p[e] /= sum;
    int i0 = 0;
#pragma unroll
    for (int e = 1; e < NEXP; ++e) if (p[e] > p[i0]) i0 = e;
    int i1 = (i0 == 0) ? 1 : 0;
#pragma unroll
    for (int e = 0; e < NEXP; ++e) if (e != i0 && p[e] > p[i1]) i1 = e;
    float w0 = p[i0], w1v = p[i1];
    float s2 = w0 + w1v;
    w0 /= s2; w1v /= s2;
    top_i[t * 2 + 0] = i0; top_i[t * 2 + 1] = i1;
    top_w[t * 2 + 0] = w0; top_w[t * 2 + 1] = w1v;
  }
}

// ---------------- plan: count + prefix + scatter, one block ----------------
__global__ __launch_bounds__(256) void plan_kernel(
    const int* __restrict__ top_i, int* __restrict__ counts,
    int* __restrict__ offsets, int* __restrict__ row_tok,
    int* __restrict__ tok_rows) {
  __shared__ int scnt[NEXP], soff[NEXP], scur[NEXP];
  int tid = threadIdx.x;
  if (tid < NEXP) { scnt[tid] = 0; scur[tid] = 0; }
  __syncthreads();
  for (int i = tid; i < T_TOK * 2; i += 256) atomicAdd(&scnt[top_i[i]], 1);
  __syncthreads();
  if (tid == 0) {
    int s = 0;
    for (int e = 0; e < NEXP; ++e) { soff[e] = s; s += scnt[e]; }
  }
  __syncthreads();
  for (int i = tid; i < T_TOK * 2; i += 256) {
    int e = top_i[i];
    int p = atomicAdd(&scur[e], 1);
    int idx = soff[e] + p;
    row_tok[idx] = i >> 1;
    tok_rows[i] = idx;
  }
  if (tid < NEXP) { counts[tid] = scnt[tid]; offsets[tid] = soff[tid]; }
  if (tid == 0) offsets[NEXP] = T_TOK * 2;
}

// ------- weight convert (grid-stride, 16B stores); launched per tensor-group -------
__global__ __launch_bounds__(256) void wconvAB_kernel(
    const float4* __restrict__ s0, const float4* __restrict__ s1,
    short8* __restrict__ d0, short8* __restrict__ d1) {
  const float4* s = blockIdx.y ? s1 : s0;
  short8* d = blockIdx.y ? d1 : d0;
  const int n8 = NEXP * FFNDIM * HID / 8;
  for (int i = blockIdx.x * 256 + threadIdx.x; i < n8; i += gridDim.x * 256) {
    float4 a = s[2 * i];
    float4 b = s[2 * i + 1];
    d[i] = pack8(a, b);
  }
}

__global__ __launch_bounds__(256) void wconvC_kernel(
    const float4* __restrict__ s, short8* __restrict__ d) {
  const int n8 = NEXP * FFNDIM * HID / 8;
  for (int i = blockIdx.x * 256 + threadIdx.x; i < n8; i += gridDim.x * 256) {
    float4 a = s[2 * i];
    float4 b = s[2 * i + 1];
    d[i] = pack8(a, b);
  }
}

// ======= GEMM1 (r8 core, BK=64): 256 tokens x 128 ffn-cols; 8 waves 2Mx4N =======
// grid: x=nt (16), y=expert (8), z=mt (8, slowest -> active blocks contiguous)
__global__ __launch_bounds__(512, 2) void gemm1_p(
    const unsigned short* __restrict__ xbf, const int* __restrict__ row_tok,
    const unsigned short* __restrict__ Wb1, const unsigned short* __restrict__ Wb3,
    const int* __restrict__ counts, const int* __restrict__ offsets,
    unsigned short* __restrict__ hbuf) {
  constexpr int BK = 64;
  constexpr int TILE = 256 * BK;
  extern __shared__ unsigned short sm1[];
  unsigned short* sA = sm1;
  unsigned short* sB = sm1 + 2 * TILE;

  int e = blockIdx.y;
  int cnt = counts[e];
  int nt = blockIdx.x, mt = blockIdx.z;
  if (cnt == 0 || mt * 256 >= cnt) return;
  int off = offsets[e];
  int ntb = nt * 128;

  int tid = threadIdx.x, lane = tid & 63, wid = tid >> 6;
  int wm = wid >> 2, wn = wid & 3;
  int fr = lane & 15, fq = lane >> 4;

  int ri = tid >> 3;
  int g = tid & 7;
  int gsw = (g ^ (ri & 7)) * 8;

  size_t asrc[4];
  const unsigned short* bsrc[4];
  int lbase[4];
#pragma unroll
  for (int j = 0; j < 4; ++j) {
    int r = j * 64 + ri;
    int rg = mt * 256 + r; if (rg > cnt - 1) rg = cnt - 1;
    int tok = row_tok[off + rg];
    asrc[j] = (size_t)tok * HID + gsw;
    int wn_ = r >> 6, s = r & 63;
    const unsigned short* mat = (s < 32) ? Wb1 : Wb3;
    bsrc[j] = mat + ((size_t)e * FFNDIM + (ntb + wn_ * 32 + (s & 31))) * HID + gsw;
    lbase[j] = (j * 64 + wid * 8) * BK;
  }

#define STAGE1(P, K0)                                                       \
  do {                                                                      \
    _Pragma("unroll")                                                       \
    for (int j = 0; j < 4; ++j) {                                           \
      gload_lds16(xbf + asrc[j] + (K0), &sA[(P) * TILE + lbase[j]]);        \
      gload_lds16(bsrc[j] + (K0), &sB[(P) * TILE + lbase[j]]);              \
    }                                                                       \
  } while (0)

  f32x4 acc[8][4];
#pragma unroll
  for (int mf = 0; mf < 8; ++mf)
#pragma unroll
    for (int nf = 0; nf < 4; ++nf) acc[mf][nf] = (f32x4){0.f, 0.f, 0.f, 0.f};

#define COMP1(P)                                                            \
  do {                                                                      \
    _Pragma("unroll")                                                       \
    for (int kk = 0; kk < 2; ++kk) {                                        \
      short8 bfr[4];                                                        \
      _Pragma("unroll")                                                     \
      for (int nf = 0; nf < 4; ++nf) {                                      \
        int R = wn * 64 + nf * 16 + fr;                                     \
        bfr[nf] = *reinterpret_cast<const short8*>(                         \
            &sB[(P) * TILE + R * BK + (((kk * 4 + fq) ^ (R & 7)) << 3)]);   \
      }                                                                     \
      _Pragma("unroll")                                                     \
      for (int mf = 0; mf < 8; ++mf) {                                      \
        int R = wm * 128 + mf * 16 + fr;                                    \
        short8 afr = *reinterpret_cast<const short8*>(                      \
            &sA[(P) * TILE + R * BK + (((kk * 4 + fq) ^ (R & 7)) << 3)]);   \
        _Pragma("unroll")                                                   \
        for (int nf = 0; nf < 4; ++nf)                                      \
          acc[mf][nf] = __builtin_amdgcn_mfma_f32_16x16x32_bf16(            \
              afr, bfr[nf], acc[mf][nf], 0, 0, 0);                          \
      }                                                                     \
    }                                                                       \
  } while (0)

  const int NT = HID / BK;   // 16
  STAGE1(0, 0);
  __syncthreads();
  int cur = 0;
  for (int t = 0; t < NT; ++t) {
    if (t + 1 < NT) STAGE1(cur ^ 1, (t + 1) * BK);
    COMP1(cur);
    __syncthreads();
    cur ^= 1;
  }

#pragma unroll
  for (int mf = 0; mf < 8; ++mf) {
    int rl = wm * 128 + mf * 16 + fq * 4;
#pragma unroll
    for (int jj = 0; jj < 4; ++jj) {
      int gm = mt * 256 + rl + jj;
      if (gm < cnt) {
#pragma unroll
        for (int nf = 0; nf < 2; ++nf) {
          float h1 = acc[mf][nf][jj];
          float h3 = acc[mf][nf + 2][jj];
          float sv = h1 / (1.f + expf(-h1)) * h3;
          hbuf[(size_t)(off + gm) * FFNDIM + ntb + wn * 32 + nf * 16 + fr] = f2bf(sv);
        }
      }
    }
  }
#undef STAGE1
#undef COMP1
}

// ======= GEMM2 (r8 core, BK=64): 256 rows x 128 hid-cols; split-K=2 =======
// grid: x=nt (8), y=zz (16: e + 8*kz), z=mt (8, slowest)
__global__ __launch_bounds__(512, 2) void gemm2_p(
    const unsigned short* __restrict__ hbuf, const unsigned short* __restrict__ Wb2,
    const int* __restrict__ counts, const int* __restrict__ offsets,
    float* __restrict__ Yg) {
  constexpr int BK = 64;
  constexpr int ATILE = 256 * BK;
  constexpr int BTILE = 128 * BK;
  extern __shared__ unsigned short sm2[];
  unsigned short* sA = sm2;
  unsigned short* sB = sm2 + 2 * ATILE;

  int zz = blockIdx.y;
  int e = zz & 7, kz = zz >> 3;
  int cnt = counts[e];
  int nt = blockIdx.x, mt = blockIdx.z;
  if (cnt == 0 || mt * 256 >= cnt) return;
  int off = offsets[e];
  int ntb = nt * 128;
  int kbase = kz * (FFNDIM / 2);

  int tid = threadIdx.x, lane = tid & 63, wid = tid >> 6;
  int wm = wid >> 2, wn = wid & 3;
  int fr = lane & 15, fq = lane >> 4;

  int ri = tid >> 3;
  int g = tid & 7;
  int gsw = (g ^ (ri & 7)) * 8;

  size_t asrc[4];
  int albase[4];
#pragma unroll
  for (int j = 0; j < 4; ++j) {
    int r = j * 64 + ri;
    int rg = mt * 256 + r; if (rg > cnt - 1) rg = cnt - 1;
    asrc[j] = (size_t)(off + rg) * FFNDIM + kbase + gsw;
    albase[j] = (j * 64 + wid * 8) * BK;
  }
  const unsigned short* bsrc[2];
  int blbase[2];
#pragma unroll
  for (int j = 0; j < 2; ++j) {
    int r = j * 64 + ri;
    bsrc[j] = Wb2 + ((size_t)e * HID + (ntb + r)) * FFNDIM + kbase + gsw;
    blbase[j] = (j * 64 + wid * 8) * BK;
  }

#define STAGE2(P, K0)                                                       \
  do {                                                                      \
    _Pragma("unroll")                                                       \
    for (int j = 0; j < 4; ++j)                                             \
      gload_lds16(hbuf + asrc[j] + (K0), &sA[(P) * ATILE + albase[j]]);     \
    _Pragma("unroll")                                                       \
    for (int j = 0; j < 2; ++j)                                             \
      gload_lds16(bsrc[j] + (K0), &sB[(P) * BTILE + blbase[j]]);            \
  } while (0)

  f32x4 acc[8][2];
#pragma unroll
  for (int mf = 0; mf < 8; ++mf)
#pragma unroll
    for (int nf = 0; nf < 2; ++nf) acc[mf][nf] = (f32x4){0.f, 0.f, 0.f, 0.f};

#define COMP2(P)                                                            \
  do {                                                                      \
    _Pragma("unroll")                                                       \
    for (int kk = 0; kk < 2; ++kk) {                                        \
      short8 bfr[2];                                                        \
      _Pragma("unroll")                                                     \
      for (int nf = 0; nf < 2; ++nf) {                                      \
        int R = wn * 32 + nf * 16 + fr;                                     \
        bfr[nf] = *reinterpret_cast<const short8*>(                         \
            &sB[(P) * BTILE + R * BK + (((kk * 4 + fq) ^ (R & 7)) << 3)]);  \
      }                                                                     \
      _Pragma("unroll")                                                     \
      for (int mf = 0; mf < 8; ++mf) {                                      \
        int R = wm * 128 + mf * 16 + fr;                                    \
        short8 afr = *reinterpret_cast<const short8*>(                      \
            &sA[(P) * ATILE + R * BK + (((kk * 4 + fq) ^ (R & 7)) << 3)]);  \
        _Pragma("unroll")                                                   \
        for (int nf = 0; nf < 2; ++nf)                                      \
          acc[mf][nf] = __builtin_amdgcn_mfma_f32_16x16x32_bf16(            \
              afr, bfr[nf], acc[mf][nf], 0, 0, 0);                          \
      }                                                                     \
    }                                                                       \
  } while (0)

  const int NT = (FFNDIM / 2) / BK;   // 16
  STAGE2(0, 0);
  __syncthreads();
  int cur = 0;
  for (int t = 0; t < NT; ++t) {
    if (t + 1 < NT) STAGE2(cur ^ 1, (t + 1) * BK);
    COMP2(cur);
    __syncthreads();
    cur ^= 1;
  }

  float* yp = Yg + (size_t)kz * (4096 * HID);
#pragma unroll
  for (int mf = 0; mf < 8; ++mf) {
    int rl = wm * 128 + mf * 16 + fq * 4;
#pragma unroll
    for (int jj = 0; jj < 4; ++jj) {
      int gm = mt * 256 + rl + jj;
      if (gm < cnt) {
#pragma unroll
        for (int nf = 0; nf < 2; ++nf)
          yp[(size_t)(off + gm) * HID + ntb + wn * 32 + nf * 16 + fr] = acc[mf][nf][jj];
      }
    }
  }
#undef STAGE2
#undef COMP2
}

// ======== combine: out[t] = tw0*(Y0[r0]+Y1[r0]) + tw1*(Y0[r1]+Y1[r1]) ========
__global__ __launch_bounds__(256) void combine_kernel(
    const float* __restrict__ Yg, const int* __restrict__ tok_rows,
    const float* __restrict__ top_w, float* __restrict__ out) {
  int t = blockIdx.x;
  int c = threadIdx.x * 4;
  int r0 = tok_rows[t * 2 + 0];
  int r1 = tok_rows[t * 2 + 1];
  float tw0 = top_w[t * 2 + 0];
  float tw1 = top_w[t * 2 + 1];
  const float* Y0 = Yg;
  const float* Y1 = Yg + (size_t)4096 * HID;
  float4 a0 = *reinterpret_cast<const float4*>(Y0 + (size_t)r0 * HID + c);
  float4 b0 = *reinterpret_cast<const float4*>(Y1 + (size_t)r0 * HID + c);
  float4 a1 = *reinterpret_cast<const float4*>(Y0 + (size_t)r1 * HID + c);
  float4 b1 = *reinterpret_cast<const float4*>(Y1 + (size_t)r1 * HID + c);
  float4 o;
  o.x = tw0 * (a0.x + b0.x) + tw1 * (a1.x + b1.x);
  o.y = tw0 * (a0.y + b0.y) + tw1 * (a1.y + b1.y);
  o.z = tw0 * (a0.z + b0.z) + tw1 * (a1.z + b1.z);
  o.w = tw0 * (a0.w + b0.w) + tw1 * (a1.w + b1.w);
  *reinterpret_cast<float4*>(out + (size_t)t * HID + c) = o;
}

extern "C" void kernel_launch(void* const* d_in, const int* in_sizes, int n_in,
                              void* d_out, int out_size, void* d_ws, size_t ws_size,
                              hipStream_t stream) {
  const float* x  = (const float*)d_in[0];
  const float* gw = (const float*)d_in[1];
  const float* w1 = (const float*)d_in[2];
  const float* w3 = (const float*)d_in[3];
  const float* w2 = (const float*)d_in[4];
  float* out = (float*)d_out;

  char* ws = (char*)d_ws;
  int*   counts   = (int*)(ws + 0);
  int*   offsets  = (int*)(ws + 64);
  int*   top_i    = (int*)(ws + 1024);
  float* top_w    = (float*)(ws + 17408);
  int*   row_tok  = (int*)(ws + 33792);
  int*   tok_rows = (int*)(ws + 50176);
  unsigned short* xbf  = (unsigned short*)(ws + 1048576);    // 4 MB
  unsigned short* hbuf = (unsigned short*)(ws + 5242880);    // 16 MB
  unsigned short* Wb1  = (unsigned short*)(ws + 22020096);   // 32 MB (aliased by Yg later)
  unsigned short* Wb3  = (unsigned short*)(ws + 55574528);   // 32 MB
  unsigned short* Wb2  = (unsigned short*)(ws + 89128960);   // 32 MB
  float*          Yg   = (float*)(ws + 22020096);            // 32 MB (aliases Wb1; gemm1 done first)

  hipFuncSetAttribute((const void*)gemm1_p,
                      hipFuncAttributeMaxDynamicSharedMemorySize, 131072);
  hipFuncSetAttribute((const void*)gemm2_p,
                      hipFuncAttributeMaxDynamicSharedMemorySize, 98304);

  router_kernel<<<T_TOK / 4, 256, 0, stream>>>(x, gw, top_i, top_w, xbf);
  plan_kernel<<<1, 256, 0, stream>>>(top_i, counts, offsets, row_tok, tok_rows);

  // Convert ONLY w1/w3 before gemm1 -> Wb1/Wb3 are the last-written 64 MB in L3
  // when gemm1 streams them (B-warmth). w2 converts between the GEMMs.
  wconvAB_kernel<<<dim3(2048, 2), 256, 0, stream>>>(
      (const float4*)w1, (const float4*)w3, (short8*)Wb1, (short8*)Wb3);

  gemm1_p<<<dim3(16, NEXP, 8), 512, 131072, stream>>>(
      xbf, row_tok, Wb1, Wb3, counts, offsets, hbuf);

  wconvC_kernel<<<2048, 256, 0, stream>>>((const float4*)w2, (short8*)Wb2);

  gemm2_p<<<dim3(8, 16, 8), 512, 98304, stream>>>(
      hbuf, Wb2, counts, offsets, Yg);
  combine_kernel<<<T_TOK, 256, 0, stream>>>(Yg, tok_rows, top_w, out);
}

// Round 16
// 177.999 us; speedup vs baseline: 1.0194x; 1.0194x over previous
//
#include <hip/hip_runtime.h>
#include <hip/hip_bf16.h>

#define T_TOK 2048
#define HID 1024
#define FFNDIM 2048
#define NEXP 8

typedef __attribute__((ext_vector_type(8))) short short8;
typedef __attribute__((ext_vector_type(4))) float f32x4;

__device__ inline unsigned short f2bf(float f) {
  union { float f; unsigned int u; } v; v.f = f;
  unsigned int u = v.u;
  unsigned int r = (u + 0x7fffu + ((u >> 16) & 1u)) >> 16;
  return (unsigned short)r;
}

__device__ inline short8 pack8(float4 a, float4 b) {
  union { __hip_bfloat162 h2[4]; short8 s; } u;
  u.h2[0] = __float22bfloat162_rn(float2{a.x, a.y});
  u.h2[1] = __float22bfloat162_rn(float2{a.z, a.w});
  u.h2[2] = __float22bfloat162_rn(float2{b.x, b.y});
  u.h2[3] = __float22bfloat162_rn(float2{b.z, b.w});
  return u.s;
}

__device__ inline void gload_lds16(const void* g, void* l) {
  __builtin_amdgcn_global_load_lds((const __attribute__((address_space(1))) void*)g,
                                   (__attribute__((address_space(3))) void*)l, 16, 0, 0);
}

// ---------------- router: logits + top2 + bf16 x copy ----------------
__global__ __launch_bounds__(256) void router_kernel(
    const float* __restrict__ x, const float* __restrict__ gw,
    int* __restrict__ top_i, float* __restrict__ top_w,
    unsigned short* __restrict__ xbf) {
  int lane = threadIdx.x & 63;
  int t = blockIdx.x * 4 + (threadIdx.x >> 6);
  if (t >= T_TOK) return;
  float xv[16];
#pragma unroll
  for (int i = 0; i < 16; ++i) xv[i] = x[(size_t)t * HID + i * 64 + lane];
#pragma unroll
  for (int i = 0; i < 16; ++i) xbf[(size_t)t * HID + i * 64 + lane] = f2bf(xv[i]);
  float logit[NEXP];
#pragma unroll
  for (int e = 0; e < NEXP; ++e) {
    float s = 0.f;
#pragma unroll
    for (int i = 0; i < 16; ++i) s += xv[i] * gw[e * HID + i * 64 + lane];
#pragma unroll
    for (int off = 32; off > 0; off >>= 1) s += __shfl_xor(s, off);
    logit[e] = s;
  }
  if (lane == 0) {
    float mx = logit[0];
#pragma unroll
    for (int e = 1; e < NEXP; ++e) mx = fmaxf(mx, logit[e]);
    float p[NEXP]; float sum = 0.f;
#pragma unroll
    for (int e = 0; e < NEXP; ++e) { p[e] = expf(logit[e] - mx); sum += p[e]; }
#pragma unroll
    for (int e = 0; e < NEXP; ++e) p[e] /= sum;
    int i0 = 0;
#pragma unroll
    for (int e = 1; e < NEXP; ++e) if (p[e] > p[i0]) i0 = e;
    int i1 = (i0 == 0) ? 1 : 0;
#pragma unroll
    for (int e = 0; e < NEXP; ++e) if (e != i0 && p[e] > p[i1]) i1 = e;
    float w0 = p[i0], w1v = p[i1];
    float s2 = w0 + w1v;
    w0 /= s2; w1v /= s2;
    top_i[t * 2 + 0] = i0; top_i[t * 2 + 1] = i1;
    top_w[t * 2 + 0] = w0; top_w[t * 2 + 1] = w1v;
  }
}

// ---------------- plan: count + prefix + scatter, one block ----------------
__global__ __launch_bounds__(256) void plan_kernel(
    const int* __restrict__ top_i, int* __restrict__ counts,
    int* __restrict__ offsets, int* __restrict__ row_tok,
    int* __restrict__ tok_rows) {
  __shared__ int scnt[NEXP], soff[NEXP], scur[NEXP];
  int tid = threadIdx.x;
  if (tid < NEXP) { scnt[tid] = 0; scur[tid] = 0; }
  __syncthreads();
  for (int i = tid; i < T_TOK * 2; i += 256) atomicAdd(&scnt[top_i[i]], 1);
  __syncthreads();
  if (tid == 0) {
    int s = 0;
    for (int e = 0; e < NEXP; ++e) { soff[e] = s; s += scnt[e]; }
  }
  __syncthreads();
  for (int i = tid; i < T_TOK * 2; i += 256) {
    int e = top_i[i];
    int p = atomicAdd(&scur[e], 1);
    int idx = soff[e] + p;
    row_tok[idx] = i >> 1;
    tok_rows[i] = idx;
  }
  if (tid < NEXP) { counts[tid] = scnt[tid]; offsets[tid] = soff[tid]; }
  if (tid == 0) offsets[NEXP] = T_TOK * 2;
}

// ---------------- weight convert: all 3 tensors, grid-stride, 16B stores ----------------
__global__ __launch_bounds__(256) void wconv_kernel(
    const float4* __restrict__ s0, const float4* __restrict__ s1,
    const float4* __restrict__ s2,
    short8* __restrict__ d0, short8* __restrict__ d1, short8* __restrict__ d2) {
  const float4* s = (blockIdx.y == 0) ? s0 : (blockIdx.y == 1) ? s1 : s2;
  short8* d = (blockIdx.y == 0) ? d0 : (blockIdx.y == 1) ? d1 : d2;
  const int n8 = NEXP * FFNDIM * HID / 8;
  for (int i = blockIdx.x * 256 + threadIdx.x; i < n8; i += gridDim.x * 256) {
    float4 a = s[2 * i];
    float4 b = s[2 * i + 1];
    d[i] = pack8(a, b);
  }
}

// ======= GEMM1 (gemm2-shaped): 128 tokens x 128 ffn-cols x {w1,w3}; BK=64 =======
// A-tile 128 rows (32 KB dbuf), B-tile 256 rows = w1/w3 interleaved (64 KB dbuf).
// 8 waves 2Mx4N; acc[4][4]=64 regs; 32 MFMA/wave/step; 96 KB LDS total.
// grid: x=nt (16), y=expert (8), z=mt (16, slowest; ~4 active per expert)
__global__ __launch_bounds__(512, 2) void gemm1_s(
    const unsigned short* __restrict__ xbf, const int* __restrict__ row_tok,
    const unsigned short* __restrict__ Wb1, const unsigned short* __restrict__ Wb3,
    const int* __restrict__ counts, const int* __restrict__ offsets,
    unsigned short* __restrict__ hbuf) {
  constexpr int BK = 64;
  constexpr int ATILE = 128 * BK;   // 8192 elems
  constexpr int BTILE = 256 * BK;   // 16384 elems
  extern __shared__ unsigned short sm1[];
  unsigned short* sA = sm1;                 // 2 * ATILE
  unsigned short* sB = sm1 + 2 * ATILE;     // 2 * BTILE

  int e = blockIdx.y;
  int cnt = counts[e];
  int nt = blockIdx.x, mt = blockIdx.z;
  if (cnt == 0 || mt * 128 >= cnt) return;
  int off = offsets[e];
  int ntb = nt * 128;

  int tid = threadIdx.x, lane = tid & 63, wid = tid >> 6;
  int wm = wid >> 2, wn = wid & 3;
  int fr = lane & 15, fq = lane >> 4;

  int ri = tid >> 3;                 // 0..63 (row within issue)
  int g = tid & 7;
  int gsw = (g ^ (ri & 7)) * 8;      // pre-swizzled source granule (elems)

  // A: 2 issues of 64 rows (token-indirected)
  size_t asrc[2]; int albase[2];
#pragma unroll
  for (int j = 0; j < 2; ++j) {
    int r = j * 64 + ri;
    int rg = mt * 128 + r; if (rg > cnt - 1) rg = cnt - 1;
    int tok = row_tok[off + rg];
    asrc[j] = (size_t)tok * HID + gsw;
    albase[j] = (j * 64 + wid * 8) * BK;
  }
  // B: 4 issues of 64 rows (w1/w3 interleaved per-32)
  const unsigned short* bsrc[4]; int blbase[4];
#pragma unroll
  for (int j = 0; j < 4; ++j) {
    int r = j * 64 + ri;
    int wn_ = r >> 6, s = r & 63;
    const unsigned short* mat = (s < 32) ? Wb1 : Wb3;
    bsrc[j] = mat + ((size_t)e * FFNDIM + (ntb + wn_ * 32 + (s & 31))) * HID + gsw;
    blbase[j] = (j * 64 + wid * 8) * BK;
  }

#define STAGE1(P, K0)                                                       \
  do {                                                                      \
    _Pragma("unroll")                                                       \
    for (int j = 0; j < 2; ++j)                                             \
      gload_lds16(xbf + asrc[j] + (K0), &sA[(P) * ATILE + albase[j]]);      \
    _Pragma("unroll")                                                       \
    for (int j = 0; j < 4; ++j)                                             \
      gload_lds16(bsrc[j] + (K0), &sB[(P) * BTILE + blbase[j]]);            \
  } while (0)

  f32x4 acc[4][4];
#pragma unroll
  for (int mf = 0; mf < 4; ++mf)
#pragma unroll
    for (int nf = 0; nf < 4; ++nf) acc[mf][nf] = (f32x4){0.f, 0.f, 0.f, 0.f};

#define COMP1(P)                                                            \
  do {                                                                      \
    _Pragma("unroll")                                                       \
    for (int kk = 0; kk < 2; ++kk) {                                        \
      short8 bfr[4];                                                        \
      _Pragma("unroll")                                                     \
      for (int nf = 0; nf < 4; ++nf) {                                      \
        int R = wn * 64 + nf * 16 + fr;                                     \
        bfr[nf] = *reinterpret_cast<const short8*>(                         \
            &sB[(P) * BTILE + R * BK + (((kk * 4 + fq) ^ (R & 7)) << 3)]);  \
      }                                                                     \
      _Pragma("unroll")                                                     \
      for (int mf = 0; mf < 4; ++mf) {                                      \
        int R = wm * 64 + mf * 16 + fr;                                     \
        short8 afr = *reinterpret_cast<const short8*>(                      \
            &sA[(P) * ATILE + R * BK + (((kk * 4 + fq) ^ (R & 7)) << 3)]);  \
        _Pragma("unroll")                                                   \
        for (int nf = 0; nf < 4; ++nf)                                      \
          acc[mf][nf] = __builtin_amdgcn_mfma_f32_16x16x32_bf16(            \
              afr, bfr[nf], acc[mf][nf], 0, 0, 0);                          \
      }                                                                     \
    }                                                                       \
  } while (0)

  const int NT = HID / BK;   // 16
  STAGE1(0, 0);
  __syncthreads();
  int cur = 0;
  for (int t = 0; t < NT; ++t) {
    if (t + 1 < NT) STAGE1(cur ^ 1, (t + 1) * BK);
    COMP1(cur);
    __syncthreads();
    cur ^= 1;
  }

#pragma unroll
  for (int mf = 0; mf < 4; ++mf) {
    int rl = wm * 64 + mf * 16 + fq * 4;
#pragma unroll
    for (int jj = 0; jj < 4; ++jj) {
      int gm = mt * 128 + rl + jj;
      if (gm < cnt) {
#pragma unroll
        for (int nf = 0; nf < 2; ++nf) {
          float h1 = acc[mf][nf][jj];
          float h3 = acc[mf][nf + 2][jj];
          float sv = h1 / (1.f + expf(-h1)) * h3;
          hbuf[(size_t)(off + gm) * FFNDIM + ntb + wn * 32 + nf * 16 + fr] = f2bf(sv);
        }
      }
    }
  }
#undef STAGE1
#undef COMP1
}

// ======= GEMM2 (r8 core, BK=64): 256 rows x 128 hid-cols; split-K=2 =======
// grid: x=nt (8), y=zz (16: e + 8*kz), z=mt (8, slowest)
__global__ __launch_bounds__(512, 2) void gemm2_p(
    const unsigned short* __restrict__ hbuf, const unsigned short* __restrict__ Wb2,
    const int* __restrict__ counts, const int* __restrict__ offsets,
    float* __restrict__ Yg) {
  constexpr int BK = 64;
  constexpr int ATILE = 256 * BK;
  constexpr int BTILE = 128 * BK;
  extern __shared__ unsigned short sm2[];
  unsigned short* sA = sm2;
  unsigned short* sB = sm2 + 2 * ATILE;

  int zz = blockIdx.y;
  int e = zz & 7, kz = zz >> 3;
  int cnt = counts[e];
  int nt = blockIdx.x, mt = blockIdx.z;
  if (cnt == 0 || mt * 256 >= cnt) return;
  int off = offsets[e];
  int ntb = nt * 128;
  int kbase = kz * (FFNDIM / 2);

  int tid = threadIdx.x, lane = tid & 63, wid = tid >> 6;
  int wm = wid >> 2, wn = wid & 3;
  int fr = lane & 15, fq = lane >> 4;

  int ri = tid >> 3;
  int g = tid & 7;
  int gsw = (g ^ (ri & 7)) * 8;

  size_t asrc[4];
  int albase[4];
#pragma unroll
  for (int j = 0; j < 4; ++j) {
    int r = j * 64 + ri;
    int rg = mt * 256 + r; if (rg > cnt - 1) rg = cnt - 1;
    asrc[j] = (size_t)(off + rg) * FFNDIM + kbase + gsw;
    albase[j] = (j * 64 + wid * 8) * BK;
  }
  const unsigned short* bsrc[2];
  int blbase[2];
#pragma unroll
  for (int j = 0; j < 2; ++j) {
    int r = j * 64 + ri;
    bsrc[j] = Wb2 + ((size_t)e * HID + (ntb + r)) * FFNDIM + kbase + gsw;
    blbase[j] = (j * 64 + wid * 8) * BK;
  }

#define STAGE2(P, K0)                                                       \
  do {                                                                      \
    _Pragma("unroll")                                                       \
    for (int j = 0; j < 4; ++j)                                             \
      gload_lds16(hbuf + asrc[j] + (K0), &sA[(P) * ATILE + albase[j]]);     \
    _Pragma("unroll")                                                       \
    for (int j = 0; j < 2; ++j)                                             \
      gload_lds16(bsrc[j] + (K0), &sB[(P) * BTILE + blbase[j]]);            \
  } while (0)

  f32x4 acc[8][2];
#pragma unroll
  for (int mf = 0; mf < 8; ++mf)
#pragma unroll
    for (int nf = 0; nf < 2; ++nf) acc[mf][nf] = (f32x4){0.f, 0.f, 0.f, 0.f};

#define COMP2(P)                                                            \
  do {                                                                      \
    _Pragma("unroll")                                                       \
    for (int kk = 0; kk < 2; ++kk) {                                        \
      short8 bfr[2];                                                        \
      _Pragma("unroll")                                                     \
      for (int nf = 0; nf < 2; ++nf) {                                      \
        int R = wn * 32 + nf * 16 + fr;                                     \
        bfr[nf] = *reinterpret_cast<const short8*>(                         \
            &sB[(P) * BTILE + R * BK + (((kk * 4 + fq) ^ (R & 7)) << 3)]);  \
      }                                                                     \
      _Pragma("unroll")                                                     \
      for (int mf = 0; mf < 8; ++mf) {                                      \
        int R = wm * 128 + mf * 16 + fr;                                    \
        short8 afr = *reinterpret_cast<const short8*>(                      \
            &sA[(P) * ATILE + R * BK + (((kk * 4 + fq) ^ (R & 7)) << 3)]);  \
        _Pragma("unroll")                                                   \
        for (int nf = 0; nf < 2; ++nf)                                      \
          acc[mf][nf] = __builtin_amdgcn_mfma_f32_16x16x32_bf16(            \
              afr, bfr[nf], acc[mf][nf], 0, 0, 0);                          \
      }                                                                     \
    }                                                                       \
  } while (0)

  const int NT = (FFNDIM / 2) / BK;   // 16
  STAGE2(0, 0);
  __syncthreads();
  int cur = 0;
  for (int t = 0; t < NT; ++t) {
    if (t + 1 < NT) STAGE2(cur ^ 1, (t + 1) * BK);
    COMP2(cur);
    __syncthreads();
    cur ^= 1;
  }

  float* yp = Yg + (size_t)kz * (4096 * HID);
#pragma unroll
  for (int mf = 0; mf < 8; ++mf) {
    int rl = wm * 128 + mf * 16 + fq * 4;
#pragma unroll
    for (int jj = 0; jj < 4; ++jj) {
      int gm = mt * 256 + rl + jj;
      if (gm < cnt) {
#pragma unroll
        for (int nf = 0; nf < 2; ++nf)
          yp[(size_t)(off + gm) * HID + ntb + wn * 32 + nf * 16 + fr] = acc[mf][nf][jj];
      }
    }
  }
#undef STAGE2
#undef COMP2
}

// ======== combine: out[t] = tw0*(Y0[r0]+Y1[r0]) + tw1*(Y0[r1]+Y1[r1]) ========
__global__ __launch_bounds__(256) void combine_kernel(
    const float* __restrict__ Yg, const int* __restrict__ tok_rows,
    const float* __restrict__ top_w, float* __restrict__ out) {
  int t = blockIdx.x;
  int c = threadIdx.x * 4;
  int r0 = tok_rows[t * 2 + 0];
  int r1 = tok_rows[t * 2 + 1];
  float tw0 = top_w[t * 2 + 0];
  float tw1 = top_w[t * 2 + 1];
  const float* Y0 = Yg;
  const float* Y1 = Yg + (size_t)4096 * HID;
  float4 a0 = *reinterpret_cast<const float4*>(Y0 + (size_t)r0 * HID + c);
  float4 b0 = *reinterpret_cast<const float4*>(Y1 + (size_t)r0 * HID + c);
  float4 a1 = *reinterpret_cast<const float4*>(Y0 + (size_t)r1 * HID + c);
  float4 b1 = *reinterpret_cast<const float4*>(Y1 + (size_t)r1 * HID + c);
  float4 o;
  o.x = tw0 * (a0.x + b0.x) + tw1 * (a1.x + b1.x);
  o.y = tw0 * (a0.y + b0.y) + tw1 * (a1.y + b1.y);
  o.z = tw0 * (a0.z + b0.z) + tw1 * (a1.z + b1.z);
  o.w = tw0 * (a0.w + b0.w) + tw1 * (a1.w + b1.w);
  *reinterpret_cast<float4*>(out + (size_t)t * HID + c) = o;
}

extern "C" void kernel_launch(void* const* d_in, const int* in_sizes, int n_in,
                              void* d_out, int out_size, void* d_ws, size_t ws_size,
                              hipStream_t stream) {
  const float* x  = (const float*)d_in[0];
  const float* gw = (const float*)d_in[1];
  const float* w1 = (const float*)d_in[2];
  const float* w3 = (const float*)d_in[3];
  const float* w2 = (const float*)d_in[4];
  float* out = (float*)d_out;

  char* ws = (char*)d_ws;
  int*   counts   = (int*)(ws + 0);
  int*   offsets  = (int*)(ws + 64);
  int*   top_i    = (int*)(ws + 1024);
  float* top_w    = (float*)(ws + 17408);
  int*   row_tok  = (int*)(ws + 33792);
  int*   tok_rows = (int*)(ws + 50176);
  unsigned short* xbf  = (unsigned short*)(ws + 1048576);    // 4 MB
  unsigned short* hbuf = (unsigned short*)(ws + 5242880);    // 16 MB
  unsigned short* Wb1  = (unsigned short*)(ws + 22020096);   // 32 MB (aliased by Yg later)
  unsigned short* Wb3  = (unsigned short*)(ws + 55574528);   // 32 MB
  unsigned short* Wb2  = (unsigned short*)(ws + 89128960);   // 32 MB
  float*          Yg   = (float*)(ws + 22020096);            // 32 MB (aliases Wb1; gemm1 done first)

  hipFuncSetAttribute((const void*)gemm1_s,
                      hipFuncAttributeMaxDynamicSharedMemorySize, 98304);
  hipFuncSetAttribute((const void*)gemm2_p,
                      hipFuncAttributeMaxDynamicSharedMemorySize, 98304);

  router_kernel<<<T_TOK / 4, 256, 0, stream>>>(x, gw, top_i, top_w, xbf);
  plan_kernel<<<1, 256, 0, stream>>>(top_i, counts, offsets, row_tok, tok_rows);
  wconv_kernel<<<dim3(2048, 3), 256, 0, stream>>>(
      (const float4*)w1, (const float4*)w3, (const float4*)w2,
      (short8*)Wb1, (short8*)Wb3, (short8*)Wb2);

  // gemm1: BM=128 -> ~512 active blocks (2 rounds of 1/CU); z=mt slowest
  gemm1_s<<<dim3(16, NEXP, 16), 512, 98304, stream>>>(
      xbf, row_tok, Wb1, Wb3, counts, offsets, hbuf);
  gemm2_p<<<dim3(8, 16, 8), 512, 98304, stream>>>(
      hbuf, Wb2, counts, offsets, Yg);
  combine_kernel<<<T_TOK, 256, 0, stream>>>(Yg, tok_rows, top_w, out);
}

// Round 17
// 175.214 us; speedup vs baseline: 1.0356x; 1.0159x over previous
//
#include <hip/hip_runtime.h>
#include <hip/hip_bf16.h>

#define T_TOK 2048
#define HID 1024
#define FFNDIM 2048
#define NEXP 8

typedef __attribute__((ext_vector_type(8))) short short8;
typedef __attribute__((ext_vector_type(4))) float f32x4;

__device__ inline unsigned short f2bf(float f) {
  union { float f; unsigned int u; } v; v.f = f;
  unsigned int u = v.u;
  unsigned int r = (u + 0x7fffu + ((u >> 16) & 1u)) >> 16;
  return (unsigned short)r;
}

__device__ inline short8 pack8(float4 a, float4 b) {
  union { __hip_bfloat162 h2[4]; short8 s; } u;
  u.h2[0] = __float22bfloat162_rn(float2{a.x, a.y});
  u.h2[1] = __float22bfloat162_rn(float2{a.z, a.w});
  u.h2[2] = __float22bfloat162_rn(float2{b.x, b.y});
  u.h2[3] = __float22bfloat162_rn(float2{b.z, b.w});
  return u.s;
}

__device__ inline void gload_lds16(const void* g, void* l) {
  __builtin_amdgcn_global_load_lds((const __attribute__((address_space(1))) void*)g,
                                   (__attribute__((address_space(3))) void*)l, 16, 0, 0);
}

#define RAW_BAR() __builtin_amdgcn_s_barrier()
#define MEMCLOB() asm volatile("" ::: "memory")

// ---------------- router: logits + top2 + bf16 x copy ----------------
__global__ __launch_bounds__(256) void router_kernel(
    const float* __restrict__ x, const float* __restrict__ gw,
    int* __restrict__ top_i, float* __restrict__ top_w,
    unsigned short* __restrict__ xbf) {
  int lane = threadIdx.x & 63;
  int t = blockIdx.x * 4 + (threadIdx.x >> 6);
  if (t >= T_TOK) return;
  float xv[16];
#pragma unroll
  for (int i = 0; i < 16; ++i) xv[i] = x[(size_t)t * HID + i * 64 + lane];
#pragma unroll
  for (int i = 0; i < 16; ++i) xbf[(size_t)t * HID + i * 64 + lane] = f2bf(xv[i]);
  float logit[NEXP];
#pragma unroll
  for (int e = 0; e < NEXP; ++e) {
    float s = 0.f;
#pragma unroll
    for (int i = 0; i < 16; ++i) s += xv[i] * gw[e * HID + i * 64 + lane];
#pragma unroll
    for (int off = 32; off > 0; off >>= 1) s += __shfl_xor(s, off);
    logit[e] = s;
  }
  if (lane == 0) {
    float mx = logit[0];
#pragma unroll
    for (int e = 1; e < NEXP; ++e) mx = fmaxf(mx, logit[e]);
    float p[NEXP]; float sum = 0.f;
#pragma unroll
    for (int e = 0; e < NEXP; ++e) { p[e] = expf(logit[e] - mx); sum += p[e]; }
#pragma unroll
    for (int e = 0; e < NEXP; ++e) p[e] /= sum;
    int i0 = 0;
#pragma unroll
    for (int e = 1; e < NEXP; ++e) if (p[e] > p[i0]) i0 = e;
    int i1 = (i0 == 0) ? 1 : 0;
#pragma unroll
    for (int e = 0; e < NEXP; ++e) if (e != i0 && p[e] > p[i1]) i1 = e;
    float w0 = p[i0], w1v = p[i1];
    float s2 = w0 + w1v;
    w0 /= s2; w1v /= s2;
    top_i[t * 2 + 0] = i0; top_i[t * 2 + 1] = i1;
    top_w[t * 2 + 0] = w0; top_w[t * 2 + 1] = w1v;
  }
}

// ---------------- plan: count + prefix + scatter, one block ----------------
__global__ __launch_bounds__(256) void plan_kernel(
    const int* __restrict__ top_i, int* __restrict__ counts,
    int* __restrict__ offsets, int* __restrict__ row_tok,
    int* __restrict__ tok_rows) {
  __shared__ int scnt[NEXP], soff[NEXP], scur[NEXP];
  int tid = threadIdx.x;
  if (tid < NEXP) { scnt[tid] = 0; scur[tid] = 0; }
  __syncthreads();
  for (int i = tid; i < T_TOK * 2; i += 256) atomicAdd(&scnt[top_i[i]], 1);
  __syncthreads();
  if (tid == 0) {
    int s = 0;
    for (int e = 0; e < NEXP; ++e) { soff[e] = s; s += scnt[e]; }
  }
  __syncthreads();
  for (int i = tid; i < T_TOK * 2; i += 256) {
    int e = top_i[i];
    int p = atomicAdd(&scur[e], 1);
    int idx = soff[e] + p;
    row_tok[idx] = i >> 1;
    tok_rows[i] = idx;
  }
  if (tid < NEXP) { counts[tid] = scnt[tid]; offsets[tid] = soff[tid]; }
  if (tid == 0) offsets[NEXP] = T_TOK * 2;
}

// ---------------- weight convert: all 3 tensors, grid-stride, 16B stores ----------------
__global__ __launch_bounds__(256) void wconv_kernel(
    const float4* __restrict__ s0, const float4* __restrict__ s1,
    const float4* __restrict__ s2,
    short8* __restrict__ d0, short8* __restrict__ d1, short8* __restrict__ d2) {
  const float4* s = (blockIdx.y == 0) ? s0 : (blockIdx.y == 1) ? s1 : s2;
  short8* d = (blockIdx.y == 0) ? d0 : (blockIdx.y == 1) ? d1 : d2;
  const int n8 = NEXP * FFNDIM * HID / 8;
  for (int i = blockIdx.x * 256 + threadIdx.x; i < n8; i += gridDim.x * 256) {
    float4 a = s[2 * i];
    float4 b = s[2 * i + 1];
    d[i] = pack8(a, b);
  }
}

// ======= GEMM1: 128 tokens x 128 ffn-cols x {w1,w3}; BK=64; RING-3 counted-vmcnt =======
// Buffers b=0..2: A at b*8192, B at 3*8192 + b*16384 (elems). 144 KB total.
// Per phase: STAGE(t+2) -> COMP(t) -> vmcnt(6) [t+1 landed] -> raw barrier.
__global__ __launch_bounds__(512, 1) void gemm1_r3(
    const unsigned short* __restrict__ xbf, const int* __restrict__ row_tok,
    const unsigned short* __restrict__ Wb1, const unsigned short* __restrict__ Wb3,
    const int* __restrict__ counts, const int* __restrict__ offsets,
    unsigned short* __restrict__ hbuf) {
  constexpr int BK = 64;
  constexpr int ATILE = 128 * BK;   // 8192 elems
  constexpr int BTILE = 256 * BK;   // 16384 elems
  extern __shared__ unsigned short sm1[];
  unsigned short* sA = sm1;                 // 3 * ATILE
  unsigned short* sB = sm1 + 3 * ATILE;     // 3 * BTILE

  int e = blockIdx.y;
  int cnt = counts[e];
  int nt = blockIdx.x, mt = blockIdx.z;
  if (cnt == 0 || mt * 128 >= cnt) return;
  int off = offsets[e];
  int ntb = nt * 128;

  int tid = threadIdx.x, lane = tid & 63, wid = tid >> 6;
  int wm = wid >> 2, wn = wid & 3;
  int fr = lane & 15, fq = lane >> 4;

  int ri = tid >> 3;
  int g = tid & 7;
  int gsw = (g ^ (ri & 7)) * 8;

  size_t asrc[2]; int albase[2];
#pragma unroll
  for (int j = 0; j < 2; ++j) {
    int r = j * 64 + ri;
    int rg = mt * 128 + r; if (rg > cnt - 1) rg = cnt - 1;
    int tok = row_tok[off + rg];
    asrc[j] = (size_t)tok * HID + gsw;
    albase[j] = (j * 64 + wid * 8) * BK;
  }
  const unsigned short* bsrc[4]; int blbase[4];
#pragma unroll
  for (int j = 0; j < 4; ++j) {
    int r = j * 64 + ri;
    int wn_ = r >> 6, s = r & 63;
    const unsigned short* mat = (s < 32) ? Wb1 : Wb3;
    bsrc[j] = mat + ((size_t)e * FFNDIM + (ntb + wn_ * 32 + (s & 31))) * HID + gsw;
    blbase[j] = (j * 64 + wid * 8) * BK;
  }

#define STAGE1(B, K0)                                                       \
  do {                                                                      \
    _Pragma("unroll")                                                       \
    for (int j = 0; j < 2; ++j)                                             \
      gload_lds16(xbf + asrc[j] + (K0), &sA[(B) * ATILE + albase[j]]);      \
    _Pragma("unroll")                                                       \
    for (int j = 0; j < 4; ++j)                                             \
      gload_lds16(bsrc[j] + (K0), &sB[(B) * BTILE + blbase[j]]);            \
  } while (0)

  f32x4 acc[4][4];
#pragma unroll
  for (int mf = 0; mf < 4; ++mf)
#pragma unroll
    for (int nf = 0; nf < 4; ++nf) acc[mf][nf] = (f32x4){0.f, 0.f, 0.f, 0.f};

#define COMP1(B)                                                            \
  do {                                                                      \
    _Pragma("unroll")                                                       \
    for (int kk = 0; kk < 2; ++kk) {                                        \
      short8 bfr[4];                                                        \
      _Pragma("unroll")                                                     \
      for (int nf = 0; nf < 4; ++nf) {                                      \
        int R = wn * 64 + nf * 16 + fr;                                     \
        bfr[nf] = *reinterpret_cast<const short8*>(                         \
            &sB[(B) * BTILE + R * BK + (((kk * 4 + fq) ^ (R & 7)) << 3)]);  \
      }                                                                     \
      _Pragma("unroll")                                                     \
      for (int mf = 0; mf < 4; ++mf) {                                      \
        int R = wm * 64 + mf * 16 + fr;                                     \
        short8 afr = *reinterpret_cast<const short8*>(                      \
            &sA[(B) * ATILE + R * BK + (((kk * 4 + fq) ^ (R & 7)) << 3)]);  \
        _Pragma("unroll")                                                   \
        for (int nf = 0; nf < 4; ++nf)                                      \
          acc[mf][nf] = __builtin_amdgcn_mfma_f32_16x16x32_bf16(            \
              afr, bfr[nf], acc[mf][nf], 0, 0, 0);                          \
      }                                                                     \
    }                                                                       \
  } while (0)

  const int NT = HID / BK;   // 16
  STAGE1(0, 0);
  STAGE1(1, BK);
  asm volatile("s_waitcnt vmcnt(6)" ::: "memory");   // tile 0 landed
  RAW_BAR(); MEMCLOB();

  int bc = 0;
  for (int t = 0; t < NT; ++t) {
    int bs = bc + 2; if (bs >= 3) bs -= 3;
    if (t + 2 < NT) STAGE1(bs, (t + 2) * BK);
    COMP1(bc);
    if (t + 1 < NT) {
      if (t + 2 < NT) asm volatile("s_waitcnt vmcnt(6)" ::: "memory");
      else            asm volatile("s_waitcnt vmcnt(0)" ::: "memory");
      RAW_BAR(); MEMCLOB();
    }
    ++bc; if (bc >= 3) bc -= 3;
  }

#pragma unroll
  for (int mf = 0; mf < 4; ++mf) {
    int rl = wm * 64 + mf * 16 + fq * 4;
#pragma unroll
    for (int jj = 0; jj < 4; ++jj) {
      int gm = mt * 128 + rl + jj;
      if (gm < cnt) {
#pragma unroll
        for (int nf = 0; nf < 2; ++nf) {
          float h1 = acc[mf][nf][jj];
          float h3 = acc[mf][nf + 2][jj];
          float sv = h1 / (1.f + expf(-h1)) * h3;
          hbuf[(size_t)(off + gm) * FFNDIM + ntb + wn * 32 + nf * 16 + fr] = f2bf(sv);
        }
      }
    }
  }
#undef STAGE1
#undef COMP1
}

// ======= GEMM2: 256 rows x 128 hid-cols; split-K=2; BK=64; RING-3 counted-vmcnt =======
__global__ __launch_bounds__(512, 1) void gemm2_r3(
    const unsigned short* __restrict__ hbuf, const unsigned short* __restrict__ Wb2,
    const int* __restrict__ counts, const int* __restrict__ offsets,
    float* __restrict__ Yg) {
  constexpr int BK = 64;
  constexpr int ATILE = 256 * BK;   // 16384 elems
  constexpr int BTILE = 128 * BK;   // 8192 elems
  extern __shared__ unsigned short sm2[];
  unsigned short* sA = sm2;               // 3 * ATILE
  unsigned short* sB = sm2 + 3 * ATILE;   // 3 * BTILE

  int zz = blockIdx.y;
  int e = zz & 7, kz = zz >> 3;
  int cnt = counts[e];
  int nt = blockIdx.x, mt = blockIdx.z;
  if (cnt == 0 || mt * 256 >= cnt) return;
  int off = offsets[e];
  int ntb = nt * 128;
  int kbase = kz * (FFNDIM / 2);

  int tid = threadIdx.x, lane = tid & 63, wid = tid >> 6;
  int wm = wid >> 2, wn = wid & 3;
  int fr = lane & 15, fq = lane >> 4;

  int ri = tid >> 3;
  int g = tid & 7;
  int gsw = (g ^ (ri & 7)) * 8;

  size_t asrc[4];
  int albase[4];
#pragma unroll
  for (int j = 0; j < 4; ++j) {
    int r = j * 64 + ri;
    int rg = mt * 256 + r; if (rg > cnt - 1) rg = cnt - 1;
    asrc[j] = (size_t)(off + rg) * FFNDIM + kbase + gsw;
    albase[j] = (j * 64 + wid * 8) * BK;
  }
  const unsigned short* bsrc[2];
  int blbase[2];
#pragma unroll
  for (int j = 0; j < 2; ++j) {
    int r = j * 64 + ri;
    bsrc[j] = Wb2 + ((size_t)e * HID + (ntb + r)) * FFNDIM + kbase + gsw;
    blbase[j] = (j * 64 + wid * 8) * BK;
  }

#define STAGE2(B, K0)                                                       \
  do {                                                                      \
    _Pragma("unroll")                                                       \
    for (int j = 0; j < 4; ++j)                                             \
      gload_lds16(hbuf + asrc[j] + (K0), &sA[(B) * ATILE + albase[j]]);     \
    _Pragma("unroll")                                                       \
    for (int j = 0; j < 2; ++j)                                             \
      gload_lds16(bsrc[j] + (K0), &sB[(B) * BTILE + blbase[j]]);            \
  } while (0)

  f32x4 acc[8][2];
#pragma unroll
  for (int mf = 0; mf < 8; ++mf)
#pragma unroll
    for (int nf = 0; nf < 2; ++nf) acc[mf][nf] = (f32x4){0.f, 0.f, 0.f, 0.f};

#define COMP2(B)                                                            \
  do {                                                                      \
    _Pragma("unroll")                                                       \
    for (int kk = 0; kk < 2; ++kk) {                                        \
      short8 bfr[2];                                                        \
      _Pragma("unroll")                                                     \
      for (int nf = 0; nf < 2; ++nf) {                                      \
        int R = wn * 32 + nf * 16 + fr;                                     \
        bfr[nf] = *reinterpret_cast<const short8*>(                         \
            &sB[(B) * BTILE + R * BK + (((kk * 4 + fq) ^ (R & 7)) << 3)]);  \
      }                                                                     \
      _Pragma("unroll")                                                     \
      for (int mf = 0; mf < 8; ++mf) {                                      \
        int R = wm * 128 + mf * 16 + fr;                                    \
        short8 afr = *reinterpret_cast<const short8*>(                      \
            &sA[(B) * ATILE + R * BK + (((kk * 4 + fq) ^ (R & 7)) << 3)]);  \
        _Pragma("unroll")                                                   \
        for (int nf = 0; nf < 2; ++nf)                                      \
          acc[mf][nf] = __builtin_amdgcn_mfma_f32_16x16x32_bf16(            \
              afr, bfr[nf], acc[mf][nf], 0, 0, 0);                          \
      }                                                                     \
    }                                                                       \
  } while (0)

  const int NT = (FFNDIM / 2) / BK;   // 16
  STAGE2(0, 0);
  STAGE2(1, BK);
  asm volatile("s_waitcnt vmcnt(6)" ::: "memory");
  RAW_BAR(); MEMCLOB();

  int bc = 0;
  for (int t = 0; t < NT; ++t) {
    int bs = bc + 2; if (bs >= 3) bs -= 3;
    if (t + 2 < NT) STAGE2(bs, (t + 2) * BK);
    COMP2(bc);
    if (t + 1 < NT) {
      if (t + 2 < NT) asm volatile("s_waitcnt vmcnt(6)" ::: "memory");
      else            asm volatile("s_waitcnt vmcnt(0)" ::: "memory");
      RAW_BAR(); MEMCLOB();
    }
    ++bc; if (bc >= 3) bc -= 3;
  }

  float* yp = Yg + (size_t)kz * (4096 * HID);
#pragma unroll
  for (int mf = 0; mf < 8; ++mf) {
    int rl = wm * 128 + mf * 16 + fq * 4;
#pragma unroll
    for (int jj = 0; jj < 4; ++jj) {
      int gm = mt * 256 + rl + jj;
      if (gm < cnt) {
#pragma unroll
        for (int nf = 0; nf < 2; ++nf)
          yp[(size_t)(off + gm) * HID + ntb + wn * 32 + nf * 16 + fr] = acc[mf][nf][jj];
      }
    }
  }
#undef STAGE2
#undef COMP2
}

// ======== combine: out[t] = tw0*(Y0[r0]+Y1[r0]) + tw1*(Y0[r1]+Y1[r1]) ========
__global__ __launch_bounds__(256) void combine_kernel(
    const float* __restrict__ Yg, const int* __restrict__ tok_rows,
    const float* __restrict__ top_w, float* __restrict__ out) {
  int t = blockIdx.x;
  int c = threadIdx.x * 4;
  int r0 = tok_rows[t * 2 + 0];
  int r1 = tok_rows[t * 2 + 1];
  float tw0 = top_w[t * 2 + 0];
  float tw1 = top_w[t * 2 + 1];
  const float* Y0 = Yg;
  const float* Y1 = Yg + (size_t)4096 * HID;
  float4 a0 = *reinterpret_cast<const float4*>(Y0 + (size_t)r0 * HID + c);
  float4 b0 = *reinterpret_cast<const float4*>(Y1 + (size_t)r0 * HID + c);
  float4 a1 = *reinterpret_cast<const float4*>(Y0 + (size_t)r1 * HID + c);
  float4 b1 = *reinterpret_cast<const float4*>(Y1 + (size_t)r1 * HID + c);
  float4 o;
  o.x = tw0 * (a0.x + b0.x) + tw1 * (a1.x + b1.x);
  o.y = tw0 * (a0.y + b0.y) + tw1 * (a1.y + b1.y);
  o.z = tw0 * (a0.z + b0.z) + tw1 * (a1.z + b1.z);
  o.w = tw0 * (a0.w + b0.w) + tw1 * (a1.w + b1.w);
  *reinterpret_cast<float4*>(out + (size_t)t * HID + c) = o;
}

extern "C" void kernel_launch(void* const* d_in, const int* in_sizes, int n_in,
                              void* d_out, int out_size, void* d_ws, size_t ws_size,
                              hipStream_t stream) {
  const float* x  = (const float*)d_in[0];
  const float* gw = (const float*)d_in[1];
  const float* w1 = (const float*)d_in[2];
  const float* w3 = (const float*)d_in[3];
  const float* w2 = (const float*)d_in[4];
  float* out = (float*)d_out;

  char* ws = (char*)d_ws;
  int*   counts   = (int*)(ws + 0);
  int*   offsets  = (int*)(ws + 64);
  int*   top_i    = (int*)(ws + 1024);
  float* top_w    = (float*)(ws + 17408);
  int*   row_tok  = (int*)(ws + 33792);
  int*   tok_rows = (int*)(ws + 50176);
  unsigned short* xbf  = (unsigned short*)(ws + 1048576);    // 4 MB
  unsigned short* hbuf = (unsigned short*)(ws + 5242880);    // 16 MB
  unsigned short* Wb1  = (unsigned short*)(ws + 22020096);   // 32 MB (aliased by Yg later)
  unsigned short* Wb3  = (unsigned short*)(ws + 55574528);   // 32 MB
  unsigned short* Wb2  = (unsigned short*)(ws + 89128960);   // 32 MB
  float*          Yg   = (float*)(ws + 22020096);            // 32 MB (aliases Wb1; gemm1 done first)

  hipFuncSetAttribute((const void*)gemm1_r3,
                      hipFuncAttributeMaxDynamicSharedMemorySize, 147456);
  hipFuncSetAttribute((const void*)gemm2_r3,
                      hipFuncAttributeMaxDynamicSharedMemorySize, 147456);

  router_kernel<<<T_TOK / 4, 256, 0, stream>>>(x, gw, top_i, top_w, xbf);
  plan_kernel<<<1, 256, 0, stream>>>(top_i, counts, offsets, row_tok, tok_rows);
  wconv_kernel<<<dim3(2048, 3), 256, 0, stream>>>(
      (const float4*)w1, (const float4*)w3, (const float4*)w2,
      (short8*)Wb1, (short8*)Wb3, (short8*)Wb2);

  gemm1_r3<<<dim3(16, NEXP, 16), 512, 147456, stream>>>(
      xbf, row_tok, Wb1, Wb3, counts, offsets, hbuf);
  gemm2_r3<<<dim3(8, 16, 8), 512, 147456, stream>>>(
      hbuf, Wb2, counts, offsets, Yg);
  combine_kernel<<<T_TOK, 256, 0, stream>>>(Yg, tok_rows, top_w, out);
}